// Round 2
// baseline (231.978 us; speedup 1.0000x reference)
//
#include <hip/hip_runtime.h>

// Input:  x (8, 32, 512, 512) fp32  -> 256 images of 512x512
// Output: LL,LH,HL,HH each (8, 32, 256, 256) fp32, concatenated flat.
//
// Per thread: 2 input rows x 16 cols (8x float4 nontemporal loads)
// -> 8 output cols in each of the 4 planes (2x float4 nt stores/plane).
// Nontemporal: input read once, output written once -> keep LLC free.

#define N_IMG   256u                  // 8*32
#define IN_W    512u
#define OUT_W   256u
#define PLANE   (N_IMG * OUT_W * OUT_W)   // 16,777,216 elements per plane

typedef float f4 __attribute__((ext_vector_type(4)));

__device__ __forceinline__ void haar4(const f4 r0, const f4 r1,
                                      float* ll, float* lh, float* hl, float* hh)
{
    // two output columns from (r0.x,r0.y,r1.x,r1.y) and (r0.z,r0.w,r1.z,r1.w)
    ll[0] = (r0.x + r0.y + r1.x + r1.y) * 0.5f;
    lh[0] = (r0.x + r0.y - r1.x - r1.y) * 0.5f;
    hl[0] = (r0.x - r0.y + r1.x - r1.y) * 0.5f;
    hh[0] = (r0.x - r0.y - r1.x + r1.y) * 0.5f;
    ll[1] = (r0.z + r0.w + r1.z + r1.w) * 0.5f;
    lh[1] = (r0.z + r0.w - r1.z - r1.w) * 0.5f;
    hl[1] = (r0.z - r0.w + r1.z - r1.w) * 0.5f;
    hh[1] = (r0.z - r0.w - r1.z + r1.w) * 0.5f;
}

__global__ __launch_bounds__(256) void dwt2d_haar_kernel(
    const float* __restrict__ x, float* __restrict__ out)
{
    unsigned t = blockIdx.x * 256u + threadIdx.x;
    // per image: 256 output rows * 32 col-groups (16 input cols each) = 8192 threads
    unsigned img = t >> 13;
    unsigned rem = t & 8191u;
    unsigned i   = rem >> 5;       // output row 0..255
    unsigned g   = rem & 31u;      // group 0..31 (input cols 16g..16g+15)

    const float* rowbase = x + (size_t)img * (IN_W * IN_W)
                             + (size_t)(2u * i) * IN_W + 16u * g;

    f4 r0[4], r1[4];
    #pragma unroll
    for (int k = 0; k < 4; ++k) {
        r0[k] = __builtin_nontemporal_load(reinterpret_cast<const f4*>(rowbase) + k);
        r1[k] = __builtin_nontemporal_load(reinterpret_cast<const f4*>(rowbase + IN_W) + k);
    }

    float ll[8], lh[8], hl[8], hh[8];
    #pragma unroll
    for (int k = 0; k < 4; ++k)
        haar4(r0[k], r1[k], ll + 2*k, lh + 2*k, hl + 2*k, hh + 2*k);

    size_t oidx = (size_t)img * (OUT_W * OUT_W) + (size_t)i * OUT_W + 8u * g;
    float* o0 = out + 0ull * PLANE + oidx;
    float* o1 = out + 1ull * PLANE + oidx;
    float* o2 = out + 2ull * PLANE + oidx;
    float* o3 = out + 3ull * PLANE + oidx;

    #pragma unroll
    for (int h = 0; h < 2; ++h) {
        f4 v;
        v.x = ll[4*h+0]; v.y = ll[4*h+1]; v.z = ll[4*h+2]; v.w = ll[4*h+3];
        __builtin_nontemporal_store(v, reinterpret_cast<f4*>(o0) + h);
        v.x = lh[4*h+0]; v.y = lh[4*h+1]; v.z = lh[4*h+2]; v.w = lh[4*h+3];
        __builtin_nontemporal_store(v, reinterpret_cast<f4*>(o1) + h);
        v.x = hl[4*h+0]; v.y = hl[4*h+1]; v.z = hl[4*h+2]; v.w = hl[4*h+3];
        __builtin_nontemporal_store(v, reinterpret_cast<f4*>(o2) + h);
        v.x = hh[4*h+0]; v.y = hh[4*h+1]; v.z = hh[4*h+2]; v.w = hh[4*h+3];
        __builtin_nontemporal_store(v, reinterpret_cast<f4*>(o3) + h);
    }
}

extern "C" void kernel_launch(void* const* d_in, const int* in_sizes, int n_in,
                              void* d_out, int out_size, void* d_ws, size_t ws_size,
                              hipStream_t stream) {
    const float* x = (const float*)d_in[0];
    float* out = (float*)d_out;
    // total threads = 256 images * 8192 = 2,097,152 -> 8192 blocks of 256
    dim3 grid(8192), block(256);
    hipLaunchKernelGGL(dwt2d_haar_kernel, grid, block, 0, stream, x, out);
}

// Round 3
// 81.143 us; speedup vs baseline: 2.8589x; 2.8589x over previous
//
#include <hip/hip_runtime.h>

// Input:  x (8, 32, 512, 512) fp32  -> 256 images of 512x512
// Output: LL,LH,HL,HH each (8, 32, 256, 256) fp32, concatenated flat.
//
// Round-1 geometry (8 input cols / thread, one float4 per plane per thread;
// wave stores are 64x16B = 1024B contiguous full-line runs) + nontemporal
// stores so the write-once output stream doesn't evict the input from LLC.

#define N_IMG   256u                  // 8*32
#define IN_W    512u
#define OUT_W   256u
#define PLANE   (N_IMG * OUT_W * OUT_W)   // 16,777,216 elements per plane

typedef float f4 __attribute__((ext_vector_type(4)));

__global__ __launch_bounds__(256) void dwt2d_haar_kernel(
    const float* __restrict__ x, float* __restrict__ out)
{
    unsigned t = blockIdx.x * 256u + threadIdx.x;
    // per image: 256 output rows * 64 quad-col groups = 16384 threads
    unsigned img = t >> 14;
    unsigned rem = t & 16383u;
    unsigned i   = rem >> 6;       // output row 0..255
    unsigned g   = rem & 63u;      // quad-col group 0..63 (input cols 8g..8g+7)

    const float* rowbase = x + (size_t)img * (IN_W * IN_W)
                             + (size_t)(2u * i) * IN_W + 8u * g;

    f4 r0a = *reinterpret_cast<const f4*>(rowbase);
    f4 r0b = *reinterpret_cast<const f4*>(rowbase + 4);
    f4 r1a = *reinterpret_cast<const f4*>(rowbase + IN_W);
    f4 r1b = *reinterpret_cast<const f4*>(rowbase + IN_W + 4);

    f4 ll, lh, hl, hh;

    ll.x = (r0a.x + r0a.y + r1a.x + r1a.y) * 0.5f;
    lh.x = (r0a.x + r0a.y - r1a.x - r1a.y) * 0.5f;
    hl.x = (r0a.x - r0a.y + r1a.x - r1a.y) * 0.5f;
    hh.x = (r0a.x - r0a.y - r1a.x + r1a.y) * 0.5f;

    ll.y = (r0a.z + r0a.w + r1a.z + r1a.w) * 0.5f;
    lh.y = (r0a.z + r0a.w - r1a.z - r1a.w) * 0.5f;
    hl.y = (r0a.z - r0a.w + r1a.z - r1a.w) * 0.5f;
    hh.y = (r0a.z - r0a.w - r1a.z + r1a.w) * 0.5f;

    ll.z = (r0b.x + r0b.y + r1b.x + r1b.y) * 0.5f;
    lh.z = (r0b.x + r0b.y - r1b.x - r1b.y) * 0.5f;
    hl.z = (r0b.x - r0b.y + r1b.x - r1b.y) * 0.5f;
    hh.z = (r0b.x - r0b.y - r1b.x + r1b.y) * 0.5f;

    ll.w = (r0b.z + r0b.w + r1b.z + r1b.w) * 0.5f;
    lh.w = (r0b.z + r0b.w - r1b.z - r1b.w) * 0.5f;
    hl.w = (r0b.z - r0b.w + r1b.z - r1b.w) * 0.5f;
    hh.w = (r0b.z - r0b.w - r1b.z + r1b.w) * 0.5f;

    size_t oidx = (size_t)img * (OUT_W * OUT_W) + (size_t)i * OUT_W + 4u * g;
    __builtin_nontemporal_store(ll, reinterpret_cast<f4*>(out + 0ull * PLANE + oidx));
    __builtin_nontemporal_store(lh, reinterpret_cast<f4*>(out + 1ull * PLANE + oidx));
    __builtin_nontemporal_store(hl, reinterpret_cast<f4*>(out + 2ull * PLANE + oidx));
    __builtin_nontemporal_store(hh, reinterpret_cast<f4*>(out + 3ull * PLANE + oidx));
}

extern "C" void kernel_launch(void* const* d_in, const int* in_sizes, int n_in,
                              void* d_out, int out_size, void* d_ws, size_t ws_size,
                              hipStream_t stream) {
    const float* x = (const float*)d_in[0];
    float* out = (float*)d_out;
    // total threads = 256 images * 16384 = 4,194,304 -> 16384 blocks of 256
    dim3 grid(16384), block(256);
    hipLaunchKernelGGL(dwt2d_haar_kernel, grid, block, 0, stream, x, out);
}